// Round 1
// baseline (409.655 us; speedup 1.0000x reference)
//
#include <hip/hip_runtime.h>
#include <hip/hip_bf16.h>

// STDP collapses to: dw = scale * (A^T @ P),  A=neurotransmitters (B=256,S=8192),
// P=action_potential (B=256,T=8192), scale=(0.05*0.05-0.01*0.05)*0.001/256.
// neuromodulators and synaptic_weights are never read.
//
// Strategy: convert+transpose A,P to bf16 (S,K)/(T,K) k-contiguous in d_ws,
// then m97-style MFMA GEMM (128x128 tile, BK=32, global_load_lds width=16).

typedef __bf16 bf16x8 __attribute__((ext_vector_type(8)));
typedef float f32x4 __attribute__((ext_vector_type(4)));

#define S_DIM 8192
#define T_DIM 8192
#define K_DIM 256

__device__ inline void async_load16(const void* g, void* lds) {
  __builtin_amdgcn_global_load_lds(
      (const __attribute__((address_space(1))) void*)g,
      (__attribute__((address_space(3))) void*)lds, 16, 0, 0);
}

// in: (K x S) fp32, out: (S x K) bf16
__global__ __launch_bounds__(256) void cvt_transpose(const float* __restrict__ in,
                                                     __bf16* __restrict__ out,
                                                     int S, int K) {
  __shared__ float tile[32][33];
  const int tx = threadIdx.x, ty = threadIdx.y;
  const int s0 = blockIdx.x * 32, k0 = blockIdx.y * 32;
#pragma unroll
  for (int j = 0; j < 4; ++j)
    tile[ty + j * 8][tx] = in[(size_t)(k0 + ty + j * 8) * S + s0 + tx];
  __syncthreads();
#pragma unroll
  for (int j = 0; j < 4; ++j)
    out[(size_t)(s0 + ty + j * 8) * K + k0 + tx] = (__bf16)tile[tx][ty + j * 8];
}

// At: (S x K) bf16, Pt: (T x K) bf16, C: (S x T) fp32
__global__ __launch_bounds__(256) void stdp_gemm(const __bf16* __restrict__ At,
                                                 const __bf16* __restrict__ Pt,
                                                 float* __restrict__ C,
                                                 float scale) {
  __shared__ __attribute__((aligned(16))) __bf16 As[128 * 32];
  __shared__ __attribute__((aligned(16))) __bf16 Bs[128 * 32];

  const int tid = threadIdx.x;
  const int wave = tid >> 6;
  const int lane = tid & 63;
  const int quad = lane >> 4;       // 0..3
  const int l16 = lane & 15;        // 0..15
  const int wm = (wave >> 1) * 64;  // wave row offset in 128x128 tile
  const int wn = (wave & 1) * 64;   // wave col offset
  const int m0 = blockIdx.y * 128;
  const int n0 = blockIdx.x * 128;

  const int r_in = lane >> 2;        // 0..15: row within a 16-row staging group
  const int kq = (lane & 3) * 8;     // 0,8,16,24: k offset within BK=32

  f32x4 acc[4][4] = {};

#pragma unroll 1
  for (int k0 = 0; k0 < K_DIM; k0 += 32) {
    // ---- stage A,B tiles: each wave stages 32 rows of each via 2+2 issues ----
#pragma unroll
    for (int i = 0; i < 2; ++i) {
      const int rbase = wave * 32 + i * 16;      // wave-uniform
      const int r = rbase + r_in;                // per-lane row
      async_load16(At + (size_t)(m0 + r) * K_DIM + k0 + kq, As + rbase * 32);
      async_load16(Pt + (size_t)(n0 + r) * K_DIM + k0 + kq, Bs + rbase * 32);
    }
    __syncthreads();  // compiler emits vmcnt(0) before s_barrier

    // ---- fragments: A[m=l16][k=quad*8+j], B[n=l16][k=quad*8+j] ----
    bf16x8 af[4], bfr[4];
#pragma unroll
    for (int i = 0; i < 4; ++i)
      af[i] = *(const bf16x8*)(As + (wm + i * 16 + l16) * 32 + quad * 8);
#pragma unroll
    for (int j = 0; j < 4; ++j)
      bfr[j] = *(const bf16x8*)(Bs + (wn + j * 16 + l16) * 32 + quad * 8);

#pragma unroll
    for (int i = 0; i < 4; ++i)
#pragma unroll
      for (int j = 0; j < 4; ++j)
        acc[i][j] = __builtin_amdgcn_mfma_f32_16x16x32_bf16(af[i], bfr[j], acc[i][j], 0, 0, 0);

    __syncthreads();
  }

  // ---- epilogue: C/D layout col=lane&15, row=quad*4+reg (m89/m91-verified) ----
#pragma unroll
  for (int i = 0; i < 4; ++i) {
    const int mrow = m0 + wm + i * 16 + quad * 4;
#pragma unroll
    for (int j = 0; j < 4; ++j) {
      const int ncol = n0 + wn + j * 16 + l16;
      float* outp = C + (size_t)mrow * T_DIM + ncol;
#pragma unroll
      for (int r = 0; r < 4; ++r)
        outp[(size_t)r * T_DIM] = acc[i][j][r] * scale;
    }
  }
}

extern "C" void kernel_launch(void* const* d_in, const int* in_sizes, int n_in,
                              void* d_out, int out_size, void* d_ws, size_t ws_size,
                              hipStream_t stream) {
  const float* pre = (const float*)d_in[0];   // neurotransmitters (B,S)
  const float* post = (const float*)d_in[2];  // action_potential (B,T)
  float* out = (float*)d_out;

  __bf16* At = (__bf16*)d_ws;                 // (S, K) bf16: 4 MB
  __bf16* Pt = At + (size_t)S_DIM * K_DIM;    // (T, K) bf16: 4 MB

  const float scale = (float)((0.05 * 0.05 - 0.01 * 0.05) * 0.001 / 256.0);

  dim3 tb(32, 8);
  cvt_transpose<<<dim3(S_DIM / 32, K_DIM / 32), tb, 0, stream>>>(pre, At, S_DIM, K_DIM);
  cvt_transpose<<<dim3(T_DIM / 32, K_DIM / 32), tb, 0, stream>>>(post, Pt, T_DIM, K_DIM);

  stdp_gemm<<<dim3(T_DIM / 128, S_DIM / 128), 256, 0, stream>>>(At, Pt, out, scale);
}

// Round 2
// 405.434 us; speedup vs baseline: 1.0104x; 1.0104x over previous
//
#include <hip/hip_runtime.h>
#include <hip/hip_bf16.h>

// STDP collapses to: dw = scale * (A^T @ P),  A=neurotransmitters (B=256,S=8192),
// P=action_potential (B=256,T=8192), scale=(0.05*0.05-0.01*0.05)*0.001/256.
// neuromodulators and synaptic_weights are never read.
//
// R2: BK=64 (4 K-iters instead of 8 -> half the vmcnt(0) barrier drains),
// XOR-swizzled LDS chunk layout (slot c of row r holds global chunk c^(r&7))
// applied at the global_load_lds source side -> conflict-free ds_read_b128
// (every aligned 8-lane group covers all 32 banks exactly once).
// cvt kernels fused into one launch via gridDim.z.

typedef __bf16 bf16x8 __attribute__((ext_vector_type(8)));
typedef float f32x4 __attribute__((ext_vector_type(4)));

#define S_DIM 8192
#define T_DIM 8192
#define K_DIM 256
#define BK 64

__device__ inline void async_load16(const void* g, void* lds) {
  __builtin_amdgcn_global_load_lds(
      (const __attribute__((address_space(1))) void*)g,
      (__attribute__((address_space(3))) void*)lds, 16, 0, 0);
}

// z=0: in0 (K x S) fp32 -> out0 (S x K) bf16;  z=1: in1 -> out1 (T x K)
__global__ __launch_bounds__(256) void cvt_transpose2(const float* __restrict__ in0,
                                                      const float* __restrict__ in1,
                                                      __bf16* __restrict__ out0,
                                                      __bf16* __restrict__ out1) {
  const float* in = blockIdx.z ? in1 : in0;
  __bf16* out = blockIdx.z ? out1 : out0;
  __shared__ float tile[32][33];
  const int tx = threadIdx.x, ty = threadIdx.y;
  const int s0 = blockIdx.x * 32, k0 = blockIdx.y * 32;
#pragma unroll
  for (int j = 0; j < 4; ++j)
    tile[ty + j * 8][tx] = in[(size_t)(k0 + ty + j * 8) * S_DIM + s0 + tx];
  __syncthreads();
#pragma unroll
  for (int j = 0; j < 4; ++j)
    out[(size_t)(s0 + ty + j * 8) * K_DIM + k0 + tx] = (__bf16)tile[tx][ty + j * 8];
}

// At: (S x K) bf16, Pt: (T x K) bf16, C: (S x T) fp32
__global__ __launch_bounds__(256) void stdp_gemm(const __bf16* __restrict__ At,
                                                 const __bf16* __restrict__ Pt,
                                                 float* __restrict__ C,
                                                 float scale) {
  __shared__ __attribute__((aligned(16))) __bf16 As[128 * BK];
  __shared__ __attribute__((aligned(16))) __bf16 Bs[128 * BK];

  const int tid = threadIdx.x;
  const int wave = tid >> 6;
  const int lane = tid & 63;
  const int quad = lane >> 4;       // 0..3
  const int l16 = lane & 15;        // 0..15
  const int wm = (wave >> 1) * 64;  // wave row offset in 128x128 tile
  const int wn = (wave & 1) * 64;   // wave col offset
  const int m0 = blockIdx.y * 128;
  const int n0 = blockIdx.x * 128;

  // staging decomposition: one issue = 64 lanes = 8 rows x 8 chunks of 16B.
  // lane L -> row rbase + (L>>3), LDS slot (L&7); global chunk = slot ^ (row&7).
  const int srow = lane >> 3;
  const int schunk = (lane & 7) ^ srow;

  f32x4 acc[4][4] = {};

#pragma unroll 1
  for (int k0 = 0; k0 < K_DIM; k0 += BK) {
    // each wave stages 32 rows of A and 32 rows of B: 4 issues each (8 rows/issue)
#pragma unroll
    for (int i = 0; i < 4; ++i) {
      const int rbase = wave * 32 + i * 8;  // wave-uniform
      async_load16(At + (size_t)(m0 + rbase + srow) * K_DIM + k0 + schunk * 8,
                   As + rbase * BK);
      async_load16(Pt + (size_t)(n0 + rbase + srow) * K_DIM + k0 + schunk * 8,
                   Bs + rbase * BK);
    }
    __syncthreads();

#pragma unroll
    for (int ks = 0; ks < 2; ++ks) {  // two k-steps of 32 within BK=64
      bf16x8 af[4], bfr[4];
#pragma unroll
      for (int i = 0; i < 4; ++i) {
        const int row = wm + i * 16 + l16;
        const int c = (ks * 4 + quad) ^ (row & 7);  // swizzled slot
        af[i] = *(const bf16x8*)(As + row * BK + c * 8);
      }
#pragma unroll
      for (int j = 0; j < 4; ++j) {
        const int row = wn + j * 16 + l16;
        const int c = (ks * 4 + quad) ^ (row & 7);
        bfr[j] = *(const bf16x8*)(Bs + row * BK + c * 8);
      }
#pragma unroll
      for (int i = 0; i < 4; ++i)
#pragma unroll
        for (int j = 0; j < 4; ++j)
          acc[i][j] = __builtin_amdgcn_mfma_f32_16x16x32_bf16(af[i], bfr[j], acc[i][j], 0, 0, 0);
    }
    __syncthreads();
  }

  // epilogue: C/D layout col=lane&15, row=quad*4+reg (m89/m91-verified)
#pragma unroll
  for (int i = 0; i < 4; ++i) {
    const int mrow = m0 + wm + i * 16 + quad * 4;
#pragma unroll
    for (int j = 0; j < 4; ++j) {
      const int ncol = n0 + wn + j * 16 + l16;
      float* outp = C + (size_t)mrow * T_DIM + ncol;
#pragma unroll
      for (int r = 0; r < 4; ++r)
        outp[(size_t)r * T_DIM] = acc[i][j][r] * scale;
    }
  }
}

extern "C" void kernel_launch(void* const* d_in, const int* in_sizes, int n_in,
                              void* d_out, int out_size, void* d_ws, size_t ws_size,
                              hipStream_t stream) {
  const float* pre = (const float*)d_in[0];   // neurotransmitters (B,S)
  const float* post = (const float*)d_in[2];  // action_potential (B,T)
  float* out = (float*)d_out;

  __bf16* At = (__bf16*)d_ws;                 // (S, K) bf16: 4 MB
  __bf16* Pt = At + (size_t)S_DIM * K_DIM;    // (T, K) bf16: 4 MB

  const float scale = (float)((0.05 * 0.05 - 0.01 * 0.05) * 0.001 / 256.0);

  cvt_transpose2<<<dim3(S_DIM / 32, K_DIM / 32, 2), dim3(32, 8), 0, stream>>>(pre, post, At, Pt);
  stdp_gemm<<<dim3(T_DIM / 128, S_DIM / 128), 256, 0, stream>>>(At, Pt, out, scale);
}